// Round 2
// baseline (199.616 us; speedup 1.0000x reference)
//
#include <hip/hip_runtime.h>

typedef short v8s __attribute__((ext_vector_type(8)));
typedef float v4f __attribute__((ext_vector_type(4)));

#define CIN   320
#define COUT  320
#define HH    64
#define WW    64
#define BN    80     // cout per block -> 4 cout-blocks, grid = 512 = exactly 2 blocks/CU
#define CIB   32
#define XS_C  40     // padded ci stride (80B rows)
#define XCOLS 66     // w = -1 .. 64
#define XROWS 6      // h0-1 .. h0+4
#define NWCH  (9*4*BN)   // 2880 16-byte weight chunks per ci-block

__device__ __forceinline__ float hf8_decode_f(int b) {
    int e = (b >> 3) & 15;
    int m = b & 7;
    // normal: (8+m) * 2^(e-17) ; subnormal: m * 2^-16
    float v = ldexpf((float)(e ? (8 + m) : m), e ? (e - 17) : -16);
    return ((b >> 7) & 1) ? -v : v;
}

__device__ __forceinline__ unsigned short f2bf(float f) {
    unsigned int u = __float_as_uint(f);
    u = (u + 0x7FFFu + ((u >> 16) & 1u)) >> 16;   // RNE
    return (unsigned short)u;
}

// w_bits [Cout][Cin][3][3] -> w_deq [9][40 cig][320 co][8 ci] bf16 (staging-friendly)
__global__ void dequant_kernel(const int* __restrict__ w_bits,
                               const int* __restrict__ b_bits,
                               unsigned short* __restrict__ w_deq,
                               float* __restrict__ b_deq) {
    int idx = blockIdx.x * 256 + threadIdx.x;   // 921600 = 3600 * 256 exactly
    int e    = idx & 7;
    int t    = idx >> 3;
    int co   = t % COUT;
    int t2   = t / COUT;
    int cig  = t2 % 40;
    int khkw = t2 / 40;
    int ci   = cig * 8 + e;
    float v = hf8_decode_f(w_bits[(co * CIN + ci) * 9 + khkw] & 0xFF);
    w_deq[idx] = (unsigned short)(__float_as_uint(v) >> 16);  // exact in bf16
    if (idx < COUT) b_deq[idx] = hf8_decode_f(b_bits[idx] & 0xFF);
}

__global__ __launch_bounds__(256, 2) void conv_mfma_kernel(
        const float* __restrict__ x,
        const unsigned short* __restrict__ w_deq,
        const float* __restrict__ b_deq,
        float* __restrict__ out) {
    __shared__ __align__(16) unsigned short xs[XROWS * XCOLS * XS_C];  // 31680 B
    __shared__ __align__(16) unsigned short wl[NWCH * 8];              // 46080 B

    const int tid  = threadIdx.x;
    const int bid  = blockIdx.x;
    const int cob  = bid >> 7;         // cob-major: same-mb blocks share an XCD (128 % 8 == 0)
    const int mb   = bid & 127;        // 8 images x 16 row-groups
    const int n    = mb >> 4;
    const int h0   = (mb & 15) << 2;   // 4 output rows per block
    const int wave = tid >> 6;         // wave w owns output row h0+w
    const int lane = tid & 63;
    const int lhi  = lane >> 4;
    const int llo  = lane & 15;
    const int ciL2 = tid & 15;         // ci pair index for x staging
    const int seg  = tid >> 4;         // 16-byte segment of an x row

    // zero the constant halo columns (global w = -1 and w = 64)
    for (int i = tid; i < XROWS * 2 * XS_C; i += 256) {
        int r  = i / (2 * XS_C);
        int tt = i - r * (2 * XS_C);
        int c  = (tt >= XS_C) ? 65 : 0;
        int ci = (tt >= XS_C) ? (tt - XS_C) : tt;
        xs[(r * XCOLS + c) * XS_C + ci] = 0;
    }

    v4f acc[4][5];
    #pragma unroll
    for (int i = 0; i < 4; ++i)
        #pragma unroll
        for (int j = 0; j < 5; ++j)
            acc[i][j] = (v4f){0.f, 0.f, 0.f, 0.f};

    // T14 prefetch registers (issue-early / write-late)
    float4 xa[XROWS], xb[XROWS];
    int4   wv[12];

    const float* xbase = x + ((size_t)(n * CIN) + 2 * ciL2) * (HH * WW);

    auto issue = [&](int ci0) {
        const float* xp0 = xbase + (size_t)ci0 * (HH * WW);
        const float* xp1 = xp0 + HH * WW;
        #pragma unroll
        for (int r = 0; r < XROWS; ++r) {
            int gh = h0 - 1 + r;
            if (gh >= 0 && gh < HH) {
                xa[r] = *(const float4*)(xp0 + gh * WW + seg * 4);
                xb[r] = *(const float4*)(xp1 + gh * WW + seg * 4);
            } else {
                xa[r] = make_float4(0.f, 0.f, 0.f, 0.f);
                xb[r] = make_float4(0.f, 0.f, 0.f, 0.f);
            }
        }
        // weight chunks: c = it*256+tid -> co = c%80, cig = (c/80)&3, khkw = c/320
        const unsigned short* wsrc =
            w_deq + ((size_t)(ci0 >> 3) * COUT + cob * BN) * 8;
        #pragma unroll
        for (int it = 0; it < 12; ++it) {
            int c = it * 256 + tid;
            if (c < NWCH) {
                int co   = c % BN;
                int q    = c / BN;
                int cig  = q & 3;
                int khkw = q >> 2;
                wv[it] = *(const int4*)(wsrc + ((size_t)(khkw * 40 + cig) * COUT + co) * 8);
            }
        }
    };

    auto write_lds = [&]() {
        #pragma unroll
        for (int r = 0; r < XROWS; ++r) {
            unsigned int p0 = (unsigned int)f2bf(xa[r].x) | ((unsigned int)f2bf(xb[r].x) << 16);
            unsigned int p1 = (unsigned int)f2bf(xa[r].y) | ((unsigned int)f2bf(xb[r].y) << 16);
            unsigned int p2 = (unsigned int)f2bf(xa[r].z) | ((unsigned int)f2bf(xb[r].z) << 16);
            unsigned int p3 = (unsigned int)f2bf(xa[r].w) | ((unsigned int)f2bf(xb[r].w) << 16);
            int cbase = r * XCOLS + 1 + seg * 4;
            *(unsigned int*)&xs[(cbase + 0) * XS_C + 2 * ciL2] = p0;
            *(unsigned int*)&xs[(cbase + 1) * XS_C + 2 * ciL2] = p1;
            *(unsigned int*)&xs[(cbase + 2) * XS_C + 2 * ciL2] = p2;
            *(unsigned int*)&xs[(cbase + 3) * XS_C + 2 * ciL2] = p3;
        }
        #pragma unroll
        for (int it = 0; it < 12; ++it) {
            int c = it * 256 + tid;
            if (c < NWCH) *(int4*)&wl[c * 8] = wv[it];
        }
    };

    auto compute = [&]() {
        #pragma unroll
        for (int khkw = 0; khkw < 9; ++khkw) {
            const int kh = khkw / 3, kw = khkw % 3;
            v8s bfr[5];
            #pragma unroll
            for (int nr = 0; nr < 5; ++nr)
                bfr[nr] = *(const v8s*)&wl[((khkw * 4 + lhi) * BN + nr * 16 + llo) * 8];
            #pragma unroll
            for (int mr = 0; mr < 4; ++mr) {
                v8s afr = *(const v8s*)&xs[((wave + kh) * XCOLS + mr * 16 + llo + kw) * XS_C + lhi * 8];
                #pragma unroll
                for (int nr = 0; nr < 5; ++nr)
                    acc[mr][nr] = __builtin_amdgcn_mfma_f32_16x16x32_bf16(
                        afr, bfr[nr], acc[mr][nr], 0, 0, 0);
            }
        }
    };

    issue(0);
    for (int t = 0; t < 10; ++t) {
        __syncthreads();                 // previous compute done -> safe to overwrite LDS
        write_lds();                     // drains vmcnt at first register use
        __syncthreads();
        if (t < 9) issue((t + 1) * CIB); // loads fly during compute(t)
        compute();
    }

    // ---- epilogue: bias + float4 stores ----
    const int h = h0 + wave;
    #pragma unroll
    for (int nr = 0; nr < 5; ++nr) {
        int co = cob * BN + nr * 16 + llo;       // D col = lane&15
        float bias = b_deq[co];
        float* op = out + ((size_t)((n * COUT + co) * HH + h)) * WW;
        #pragma unroll
        for (int mr = 0; mr < 4; ++mr) {
            int wc = mr * 16 + lhi * 4;          // D row = (lane>>4)*4 + reg
            float4 o;
            o.x = acc[mr][nr][0] + bias;
            o.y = acc[mr][nr][1] + bias;
            o.z = acc[mr][nr][2] + bias;
            o.w = acc[mr][nr][3] + bias;
            *(float4*)(op + wc) = o;
        }
    }
}

extern "C" void kernel_launch(void* const* d_in, const int* in_sizes, int n_in,
                              void* d_out, int out_size, void* d_ws, size_t ws_size,
                              hipStream_t stream) {
    const float* x      = (const float*)d_in[0];
    const int*   w_bits = (const int*)d_in[1];
    const int*   b_bits = (const int*)d_in[2];
    float*       out    = (float*)d_out;

    unsigned short* w_deq = (unsigned short*)d_ws;                       // 1,843,200 B
    float*          b_deq = (float*)((char*)d_ws + (size_t)9 * 40 * COUT * 8 * 2);

    dequant_kernel<<<3600, 256, 0, stream>>>(w_bits, b_bits, w_deq, b_deq);

    // grid: 4 cout-blocks x (8 images x 16 row-groups) = 512 workgroups = 2/CU, no tail
    conv_mfma_kernel<<<512, 256, 0, stream>>>(x, w_deq, b_deq, out);
}

// Round 3
// 63.712 us; speedup vs baseline: 3.1331x; 3.1331x over previous
//
#include <hip/hip_runtime.h>
#include <stdint.h>

typedef short v8s __attribute__((ext_vector_type(8)));
typedef float v4f __attribute__((ext_vector_type(4)));

#define CIN   320
#define COUT  320
#define HH    64
#define WW    64
#define BN    80     // cout per block -> 4 cout-blocks, grid = 512 = exactly 2 blocks/CU
#define CIB   32
#define XS_C  40     // padded ci stride (80B rows) for x tile
#define XCOLS 66     // w = -1 .. 64
#define XROWS 6      // h0-1 .. h0+4
#define NWCH  (9*4*BN)   // 2880 16-byte weight chunks per ci-block
#define NWL   (NWCH/64)  // 45 wave-wide global_load_lds per ci-block

__device__ __forceinline__ float hf8_decode_f(int b) {
    int e = (b >> 3) & 15;
    int m = b & 7;
    // normal: (8+m) * 2^(e-17) ; subnormal: m * 2^-16
    float v = ldexpf((float)(e ? (8 + m) : m), e ? (e - 17) : -16);
    return ((b >> 7) & 1) ? -v : v;
}

// w_bits [Cout][Cin][3][3] -> w_deq [9][40 cig][320 co][8 ci] bf16 (LDS-final layout)
__global__ void dequant_kernel(const int* __restrict__ w_bits,
                               const int* __restrict__ b_bits,
                               unsigned short* __restrict__ w_deq,
                               float* __restrict__ b_deq) {
    int idx = blockIdx.x * 256 + threadIdx.x;   // 921600 = 3600 * 256 exactly
    int e    = idx & 7;
    int t    = idx >> 3;
    int co   = t % COUT;
    int t2   = t / COUT;
    int cig  = t2 % 40;
    int khkw = t2 / 40;
    int ci   = cig * 8 + e;
    float v = hf8_decode_f(w_bits[(co * CIN + ci) * 9 + khkw] & 0xFF);
    w_deq[idx] = (unsigned short)(__float_as_uint(v) >> 16);  // exact in bf16
    if (idx < COUT) b_deq[idx] = hf8_decode_f(b_bits[idx] & 0xFF);
}

__device__ __forceinline__ unsigned int cvt_pk_bf16(float lo, float hi) {
    unsigned int r;
    asm("v_cvt_pk_bf16_f32 %0, %1, %2" : "=v"(r) : "v"(lo), "v"(hi));
    return r;
}

__global__ __launch_bounds__(256, 2) void conv_mfma_kernel(
        const float* __restrict__ x,
        const unsigned short* __restrict__ w_deq,
        const float* __restrict__ b_deq,
        float* __restrict__ out) {
    __shared__ __align__(16) unsigned short xs[XROWS * XCOLS * XS_C];  // 31680 B
    __shared__ __align__(16) unsigned short wl[NWCH * 8];              // 46080 B

    const int tid  = threadIdx.x;
    const int bid  = blockIdx.x;
    const int cob  = bid >> 7;         // cob-major: same-x blocks adjacent (128 % 8 == 0)
    const int mb   = bid & 127;        // 8 images x 16 row-groups
    const int n    = mb >> 4;
    const int h0   = (mb & 15) << 2;   // 4 output rows per block
    const int wave = tid >> 6;         // wave w owns output row h0+w
    const int lane = tid & 63;
    const int lhi  = lane >> 4;
    const int llo  = lane & 15;
    const int ciL2 = tid & 15;         // ci pair index for x staging
    const int seg  = tid >> 4;         // 16-byte segment of an x row

    // zero the constant halo columns (global w = -1 and w = 64) once
    for (int i = tid; i < XROWS * 2 * XS_C; i += 256) {
        int r  = i / (2 * XS_C);
        int tt = i - r * (2 * XS_C);
        int c  = (tt >= XS_C) ? 65 : 0;
        int ci = (tt >= XS_C) ? (tt - XS_C) : tt;
        xs[(r * XCOLS + c) * XS_C + ci] = 0;
    }

    v4f acc[4][5];
    #pragma unroll
    for (int i = 0; i < 4; ++i)
        #pragma unroll
        for (int j = 0; j < 5; ++j)
            acc[i][j] = (v4f){0.f, 0.f, 0.f, 0.f};

    // per-lane byte offsets for the weight global_load_lds chunks (constant per tile)
    int woff[12];
    #pragma unroll
    for (int ii = 0; ii < 12; ++ii) {
        int i = wave + ii * 4;
        if (i < NWL) {
            int c    = i * 64 + lane;        // chunk index, matches LDS position c*16B
            int co   = c % BN;
            int q    = c / BN;
            int cig  = q & 3;
            int khkw = q >> 2;
            woff[ii] = ((khkw * 40 + cig) * COUT + cob * BN + co) * 16;
        } else {
            woff[ii] = 0;
        }
    }

    const float* xbase = x + ((size_t)(n * CIN) + 2 * ciL2) * (HH * WW);

    for (int t = 0; t < 10; ++t) {
        const int ci0 = t * CIB;
        __syncthreads();                 // previous compute done -> safe to overwrite LDS

        // ---- issue x global loads (batched) ----
        float4 xa[XROWS], xb[XROWS];
        {
            const float* xp0 = xbase + (size_t)ci0 * (HH * WW);
            const float* xp1 = xp0 + HH * WW;
            #pragma unroll
            for (int r = 0; r < XROWS; ++r) {
                int gh = h0 - 1 + r;
                if (gh >= 0 && gh < HH) {
                    xa[r] = *(const float4*)(xp0 + gh * WW + seg * 4);
                    xb[r] = *(const float4*)(xp1 + gh * WW + seg * 4);
                } else {
                    xa[r] = make_float4(0.f, 0.f, 0.f, 0.f);
                    xb[r] = make_float4(0.f, 0.f, 0.f, 0.f);
                }
            }
        }

        // ---- issue weight global -> LDS direct copies (no register round-trip) ----
        {
            const char* wb = (const char*)w_deq + (size_t)(ci0 >> 3) * (COUT * 16);
            #pragma unroll
            for (int ii = 0; ii < 12; ++ii) {
                int i = wave + ii * 4;
                if (i < NWL) {
                    const unsigned int* gsrc = (const unsigned int*)(wb + woff[ii]);
                    unsigned short* ldst = &wl[i * 512];
                    __builtin_amdgcn_global_load_lds(
                        (const __attribute__((address_space(1))) unsigned int*)(uintptr_t)gsrc,
                        (__attribute__((address_space(3))) unsigned int*)(uintptr_t)ldst,
                        16, 0, 0);
                }
            }
        }

        // ---- convert + write x to LDS (waits x loads via counted vmcnt) ----
        #pragma unroll
        for (int r = 0; r < XROWS; ++r) {
            unsigned int p0 = cvt_pk_bf16(xa[r].x, xb[r].x);
            unsigned int p1 = cvt_pk_bf16(xa[r].y, xb[r].y);
            unsigned int p2 = cvt_pk_bf16(xa[r].z, xb[r].z);
            unsigned int p3 = cvt_pk_bf16(xa[r].w, xb[r].w);
            int cbase = r * XCOLS + 1 + seg * 4;
            *(unsigned int*)&xs[(cbase + 0) * XS_C + 2 * ciL2] = p0;
            *(unsigned int*)&xs[(cbase + 1) * XS_C + 2 * ciL2] = p1;
            *(unsigned int*)&xs[(cbase + 2) * XS_C + 2 * ciL2] = p2;
            *(unsigned int*)&xs[(cbase + 3) * XS_C + 2 * ciL2] = p3;
        }

        __syncthreads();                 // drains vmcnt(0): weights landed, x written

        // ---- compute: 9 taps x 20 MFMA ----
        #pragma unroll
        for (int khkw = 0; khkw < 9; ++khkw) {
            const int kh = khkw / 3, kw = khkw % 3;
            v8s bfr[5];
            #pragma unroll
            for (int nr = 0; nr < 5; ++nr)
                bfr[nr] = *(const v8s*)&wl[((khkw * 4 + lhi) * BN + nr * 16 + llo) * 8];
            #pragma unroll
            for (int mr = 0; mr < 4; ++mr) {
                v8s afr = *(const v8s*)&xs[((wave + kh) * XCOLS + mr * 16 + llo + kw) * XS_C + lhi * 8];
                #pragma unroll
                for (int nr = 0; nr < 5; ++nr)
                    acc[mr][nr] = __builtin_amdgcn_mfma_f32_16x16x32_bf16(
                        afr, bfr[nr], acc[mr][nr], 0, 0, 0);
            }
        }
    }

    // ---- epilogue: bias + float4 stores ----
    const int h = h0 + wave;
    #pragma unroll
    for (int nr = 0; nr < 5; ++nr) {
        int co = cob * BN + nr * 16 + llo;       // D col = lane&15
        float bias = b_deq[co];
        float* op = out + ((size_t)((n * COUT + co) * HH + h)) * WW;
        #pragma unroll
        for (int mr = 0; mr < 4; ++mr) {
            int wc = mr * 16 + lhi * 4;          // D row = (lane>>4)*4 + reg
            float4 o;
            o.x = acc[mr][nr][0] + bias;
            o.y = acc[mr][nr][1] + bias;
            o.z = acc[mr][nr][2] + bias;
            o.w = acc[mr][nr][3] + bias;
            *(float4*)(op + wc) = o;
        }
    }
}

extern "C" void kernel_launch(void* const* d_in, const int* in_sizes, int n_in,
                              void* d_out, int out_size, void* d_ws, size_t ws_size,
                              hipStream_t stream) {
    const float* x      = (const float*)d_in[0];
    const int*   w_bits = (const int*)d_in[1];
    const int*   b_bits = (const int*)d_in[2];
    float*       out    = (float*)d_out;

    unsigned short* w_deq = (unsigned short*)d_ws;                       // 1,843,200 B
    float*          b_deq = (float*)((char*)d_ws + (size_t)9 * 40 * COUT * 8 * 2);

    dequant_kernel<<<3600, 256, 0, stream>>>(w_bits, b_bits, w_deq, b_deq);

    // grid: 4 cout-blocks x (8 images x 16 row-groups) = 512 workgroups = 2/CU, no tail
    conv_mfma_kernel<<<512, 256, 0, stream>>>(x, w_deq, b_deq, out);
}